// Round 3
// baseline (195.502 us; speedup 1.0000x reference)
//
#include <hip/hip_runtime.h>

// Problem constants (from reference)
#define NB 64      // B
#define NC 23      // C
#define NL 26000   // L
#define ND 64      // D
#define NE 512     // E
#define NK 3       // K
#define NCL (NC * NL)            // 598000
#define NTOT ((size_t)NB * NCL * NK)   // 114,816,000 output floats (divisible by 4 and 3)

// ---------------------------------------------------------------------------
// Kernel 1: e[b,c,k] = fc_b[k] + sum_d We[k,d] * (eos_b[d] + sum_e eos_emb[b,c,e]*eos_W[d,e])
// One 64-thread block per (b,c) pair.  ~48M MACs, tiny.
// ---------------------------------------------------------------------------
__global__ __launch_bounds__(64) void eos_e_kernel(
    const float* __restrict__ eos_emb,  // [B][C][E]
    const float* __restrict__ eos_W,    // [D][E]
    const float* __restrict__ eos_b,    // [D]
    const float* __restrict__ fc_W,     // [K][2D]
    const float* __restrict__ fc_b,     // [K]
    float* __restrict__ e_out)          // [B*C][K]
{
    const int bc = blockIdx.x;          // b*C + c
    const int d  = threadIdx.x;         // 0..63

    __shared__ float xs[NE];
    float4* xs4 = reinterpret_cast<float4*>(xs);
    const float4* src = reinterpret_cast<const float4*>(eos_emb + (size_t)bc * NE);
    for (int i = d; i < NE / 4; i += 64) xs4[i] = src[i];
    __syncthreads();

    const float4* wrow = reinterpret_cast<const float4*>(eos_W + (size_t)d * NE);
    float acc = 0.f;
    #pragma unroll 8
    for (int i = 0; i < NE / 4; ++i) {
        float4 w = wrow[i];
        float4 x = xs4[i];
        acc += w.x * x.x;
        acc += w.y * x.y;
        acc += w.z * x.z;
        acc += w.w * x.w;
    }
    const float eosd = acc + eos_b[d];

    #pragma unroll
    for (int k = 0; k < NK; ++k) {
        float p = eosd * fc_W[k * (2 * ND) + ND + d];   // We[k][d]
        #pragma unroll
        for (int off = 32; off > 0; off >>= 1) p += __shfl_xor(p, off, 64);
        if (d == 0) e_out[(size_t)bc * NK + k] = p + fc_b[k];
    }
}

// ---------------------------------------------------------------------------
// Kernel A: a[c,l,k] = dot(emb_table[bin_ids[c,l]], Wb[k])  -> workspace.
// Read-dominated (153 MB in, 7.2 MB out).
// ---------------------------------------------------------------------------
__global__ __launch_bounds__(256) void a_kernel(
    const int*   __restrict__ bin_ids,    // [C][L]
    const float* __restrict__ emb_table,  // [V][D]
    const float* __restrict__ fc_W,       // [K][2D]
    float* __restrict__ a_out)            // [C][L][K]
{
    const int c   = blockIdx.y;
    const int tid = threadIdx.x;
    const int l   = blockIdx.x * 256 + tid;

    __shared__ float wb[NK][ND];
    if (tid < NK * ND)
        wb[tid / ND][tid % ND] = fc_W[(tid / ND) * (2 * ND) + (tid % ND)];
    __syncthreads();
    if (l >= NL) return;

    const int row = bin_ids[(size_t)c * NL + l];
    const float4* er = reinterpret_cast<const float4*>(emb_table + (size_t)row * ND);
    const float4* w0 = reinterpret_cast<const float4*>(wb[0]);
    const float4* w1 = reinterpret_cast<const float4*>(wb[1]);
    const float4* w2 = reinterpret_cast<const float4*>(wb[2]);

    float a0 = 0.f, a1 = 0.f, a2 = 0.f;
    #pragma unroll
    for (int i = 0; i < ND / 4; ++i) {
        float4 v  = er[i];
        float4 p0 = w0[i], p1 = w1[i], p2 = w2[i];
        a0 += v.x * p0.x + v.y * p0.y + v.z * p0.z + v.w * p0.w;
        a1 += v.x * p1.x + v.y * p1.y + v.z * p1.z + v.w * p1.w;
        a2 += v.x * p2.x + v.y * p2.y + v.z * p2.z + v.w * p2.w;
    }

    float* dst = a_out + ((size_t)c * NL + l) * NK;
    dst[0] = a0; dst[1] = a1; dst[2] = a2;
}

// ---------------------------------------------------------------------------
// Kernel B (flat): thread i writes out[4i .. 4i+3] as ONE float4 store —
// structurally identical to the 6.7 TB/s fill kernel (monotone flat sweep,
// 16 B/lane).  Reads: a (7.2 MB, L2/L3-resident) + e (17 KB, L1-resident).
//   n = ((b*C + c)*L + l)*3 + k ;  m = n/3 = (b*C+c)*L + l
//   4 consecutive n span exactly m0 and m0+1.
// ---------------------------------------------------------------------------
__global__ __launch_bounds__(256) void store_flat_kernel(
    const float* __restrict__ a_in,   // [C*L][3]
    const float* __restrict__ e_in,   // [B*C][3]
    float* __restrict__ out)          // [NTOT]
{
    const long long i = (long long)blockIdx.x * 256 + threadIdx.x;
    if (i >= (long long)(NTOT / 4)) return;

    const long long n0 = i * 4;
    const long long m0 = n0 / 3;          // (b*C+c)*L + l
    const int       k0 = (int)(n0 - m0 * 3);   // = i % 3

    // decode m0 -> (b0, j0=c*L+l, c0, l0)
    const int b0 = (int)(m0 / NCL);
    const int j0 = (int)(m0 - (long long)b0 * NCL);
    const int c0 = j0 / NL;
    const int l0 = j0 - c0 * NL;

    // m1 = m0 + 1 with carries (never reaches B*C*L — proven by N%4==0, N%3==0)
    int b1 = b0, c1 = c0, j1 = j0 + 1;
    if (l0 + 1 == NL) {
        if (c0 + 1 == NC) { b1 = b0 + 1; c1 = 0; }
        else              { c1 = c0 + 1; }
    }

    const float* ap0 = a_in + (size_t)j0 * 3;
    const float* ap1 = a_in + (size_t)j1 * 3;
    const float* ep0 = e_in + ((size_t)b0 * NC + c0) * 3;
    const float* ep1 = e_in + ((size_t)b1 * NC + c1) * 3;

    const float r0 = fmaxf(ap0[0] + ep0[0], 0.f);
    const float r1 = fmaxf(ap0[1] + ep0[1], 0.f);
    const float r2 = fmaxf(ap0[2] + ep0[2], 0.f);
    const float s0 = fmaxf(ap1[0] + ep1[0], 0.f);
    const float s1 = fmaxf(ap1[1] + ep1[1], 0.f);
    const float s2 = fmaxf(ap1[2] + ep1[2], 0.f);

    float4 o;
    if (k0 == 0)      { o.x = r0; o.y = r1; o.z = r2; o.w = s0; }
    else if (k0 == 1) { o.x = r1; o.y = r2; o.z = s0; o.w = s1; }
    else              { o.x = r2; o.y = s0; o.z = s1; o.w = s2; }

    reinterpret_cast<float4*>(out)[i] = o;
}

// ---------------------------------------------------------------------------
// Fused fallback for the case ws_size is too small.
// ---------------------------------------------------------------------------
__global__ __launch_bounds__(256) void decoder_fused_kernel(
    const int*   __restrict__ bin_ids,
    const float* __restrict__ emb_table,
    const float* __restrict__ fc_W,
    const float* __restrict__ e_in,
    float* __restrict__ out)
{
    const int c   = blockIdx.y;
    const int tid = threadIdx.x;
    const int l   = blockIdx.x * 256 + tid;

    __shared__ float wb[NK][ND];
    __shared__ float es[NB * NK];

    if (tid < NK * ND)
        wb[tid / ND][tid % ND] = fc_W[(tid / ND) * (2 * ND) + (tid % ND)];
    if (tid < NB * NK) {
        int b = tid / NK, k = tid % NK;
        es[tid] = e_in[((size_t)b * NC + c) * NK + k];
    }
    __syncthreads();
    if (l >= NL) return;

    const int row = bin_ids[(size_t)c * NL + l];
    const float4* er = reinterpret_cast<const float4*>(emb_table + (size_t)row * ND);
    const float4* w0 = reinterpret_cast<const float4*>(wb[0]);
    const float4* w1 = reinterpret_cast<const float4*>(wb[1]);
    const float4* w2 = reinterpret_cast<const float4*>(wb[2]);

    float a0 = 0.f, a1 = 0.f, a2 = 0.f;
    #pragma unroll
    for (int i = 0; i < ND / 4; ++i) {
        float4 v  = er[i];
        float4 p0 = w0[i], p1 = w1[i], p2 = w2[i];
        a0 += v.x * p0.x + v.y * p0.y + v.z * p0.z + v.w * p0.w;
        a1 += v.x * p1.x + v.y * p1.y + v.z * p1.z + v.w * p1.w;
        a2 += v.x * p2.x + v.y * p2.y + v.z * p2.z + v.w * p2.w;
    }

    size_t obase = ((size_t)c * NL + l) * NK;
    const size_t bstride = (size_t)NC * NL * NK;
    #pragma unroll 4
    for (int b = 0; b < NB; ++b) {
        const float e0 = es[b * NK + 0];
        const float e1 = es[b * NK + 1];
        const float e2 = es[b * NK + 2];
        out[obase + 0] = fmaxf(a0 + e0, 0.f);
        out[obase + 1] = fmaxf(a1 + e1, 0.f);
        out[obase + 2] = fmaxf(a2 + e2, 0.f);
        obase += bstride;
    }
}

extern "C" void kernel_launch(void* const* d_in, const int* in_sizes, int n_in,
                              void* d_out, int out_size, void* d_ws, size_t ws_size,
                              hipStream_t stream) {
    const float* eos_emb   = (const float*)d_in[0];
    const int*   bin_ids   = (const int*)  d_in[1];
    const float* emb_table = (const float*)d_in[2];
    const float* eos_W     = (const float*)d_in[3];
    const float* eos_b     = (const float*)d_in[4];
    const float* fc_W      = (const float*)d_in[5];
    const float* fc_b      = (const float*)d_in[6];
    float*       out       = (float*)d_out;

    // ws layout: [0, 32 KB) -> e (B*C*K floats); [32 KB, ...) -> a (C*L*K floats)
    float*  e_ws = (float*)d_ws;
    const size_t a_off_bytes = 32768;
    float*  a_ws = (float*)((char*)d_ws + a_off_bytes);
    const size_t a_bytes = (size_t)NC * NL * NK * sizeof(float);

    eos_e_kernel<<<NB * NC, 64, 0, stream>>>(eos_emb, eos_W, eos_b, fc_W, fc_b, e_ws);

    if (ws_size >= a_off_bytes + a_bytes) {
        dim3 grid((NL + 255) / 256, NC);
        a_kernel<<<grid, 256, 0, stream>>>(bin_ids, emb_table, fc_W, a_ws);

        const long long nthreads = (long long)(NTOT / 4);
        const int nblocks = (int)((nthreads + 255) / 256);
        store_flat_kernel<<<nblocks, 256, 0, stream>>>(a_ws, e_ws, out);
    } else {
        dim3 grid((NL + 255) / 256, NC);
        decoder_fused_kernel<<<grid, 256, 0, stream>>>(bin_ids, emb_table, fc_W, e_ws, out);
    }
}

// Round 5
// 161.966 us; speedup vs baseline: 1.2071x; 1.2071x over previous
//
#include <hip/hip_runtime.h>

// Problem constants (from reference)
#define NB 64      // B
#define NC 23      // C
#define NL 26000   // L
#define ND 64      // D
#define NE 512     // E
#define NK 3       // K
#define NCL (NC * NL)                  // 598000
#define FP4 (NL * NK / 4)              // 19500 float4s per (b,c) slice
#define BSTRIDE4 ((size_t)NC * FP4)    // 448500 float4s per b step

typedef float v4f __attribute__((ext_vector_type(4)));

// ---------------------------------------------------------------------------
// Kernel 1: e[b,c,k] = fc_b[k] + sum_d We[k,d]*(eos_b[d] + eos_emb[b,c,:]·eos_W[d,:])
// ---------------------------------------------------------------------------
__global__ __launch_bounds__(64) void eos_e_kernel(
    const float* __restrict__ eos_emb,  // [B][C][E]
    const float* __restrict__ eos_W,    // [D][E]
    const float* __restrict__ eos_b,    // [D]
    const float* __restrict__ fc_W,     // [K][2D]
    const float* __restrict__ fc_b,     // [K]
    float* __restrict__ e_out)          // [B*C][K]
{
    const int bc = blockIdx.x;
    const int d  = threadIdx.x;

    __shared__ float xs[NE];
    float4* xs4 = reinterpret_cast<float4*>(xs);
    const float4* src = reinterpret_cast<const float4*>(eos_emb + (size_t)bc * NE);
    for (int i = d; i < NE / 4; i += 64) xs4[i] = src[i];
    __syncthreads();

    const float4* wrow = reinterpret_cast<const float4*>(eos_W + (size_t)d * NE);
    float acc = 0.f;
    #pragma unroll 8
    for (int i = 0; i < NE / 4; ++i) {
        float4 w = wrow[i];
        float4 x = xs4[i];
        acc += w.x * x.x;
        acc += w.y * x.y;
        acc += w.z * x.z;
        acc += w.w * x.w;
    }
    const float eosd = acc + eos_b[d];

    #pragma unroll
    for (int k = 0; k < NK; ++k) {
        float p = eosd * fc_W[k * (2 * ND) + ND + d];   // We[k][d]
        #pragma unroll
        for (int off = 32; off > 0; off >>= 1) p += __shfl_xor(p, off, 64);
        if (d == 0) e_out[(size_t)bc * NK + k] = p + fc_b[k];
    }
}

// ---------------------------------------------------------------------------
// Kernel A: a[c,l,k] = dot(emb_table[bin_ids[c,l]], Wb[k])  -> workspace.
// ---------------------------------------------------------------------------
__global__ __launch_bounds__(256) void a_kernel(
    const int*   __restrict__ bin_ids,    // [C][L]
    const float* __restrict__ emb_table,  // [V][D]
    const float* __restrict__ fc_W,       // [K][2D]
    float* __restrict__ a_out)            // [C][L][K]
{
    const int c   = blockIdx.y;
    const int tid = threadIdx.x;
    const int l   = blockIdx.x * 256 + tid;

    __shared__ float wb[NK][ND];
    if (tid < NK * ND)
        wb[tid / ND][tid % ND] = fc_W[(tid / ND) * (2 * ND) + (tid % ND)];
    __syncthreads();
    if (l >= NL) return;

    const int row = bin_ids[(size_t)c * NL + l];
    const float4* er = reinterpret_cast<const float4*>(emb_table + (size_t)row * ND);
    const float4* w0 = reinterpret_cast<const float4*>(wb[0]);
    const float4* w1 = reinterpret_cast<const float4*>(wb[1]);
    const float4* w2 = reinterpret_cast<const float4*>(wb[2]);

    float a0 = 0.f, a1 = 0.f, a2 = 0.f;
    #pragma unroll
    for (int i = 0; i < ND / 4; ++i) {
        float4 v  = er[i];
        float4 p0 = w0[i], p1 = w1[i], p2 = w2[i];
        a0 += v.x * p0.x + v.y * p0.y + v.z * p0.z + v.w * p0.w;
        a1 += v.x * p1.x + v.y * p1.y + v.z * p1.z + v.w * p1.w;
        a2 += v.x * p2.x + v.y * p2.y + v.z * p2.z + v.w * p2.w;
    }

    float* dst = a_out + ((size_t)c * NL + l) * NK;
    dst[0] = a0; dst[1] = a1; dst[2] = a2;
}

// ---------------------------------------------------------------------------
// Kernel B: b-stream store.  Block = (c, 1024-l chunk).  Each thread holds 3
// a-float4s in registers (read once, b-invariant); per b: 3 LDS broadcast
// reads of the phase-rotated e vector + 3 contiguous float4 NT stores.
// Per b each block writes one contiguous 12 KB run.
// ---------------------------------------------------------------------------
__global__ __launch_bounds__(256) void bstream_kernel(
    const float* __restrict__ a_in,   // [C][L][K] floats (= C*19500 float4)
    const float* __restrict__ e_in,   // [B*C][K]
    float* __restrict__ out)          // [B][C][L][K]
{
    const int c  = blockIdx.y;
    const int bx = blockIdx.x;
    const int t  = threadIdx.x;

    // e4[p][b] = (e[p], e[(p+1)%3], e[(p+2)%3], e[p]) ; padded row stride 66
    __shared__ v4f e4[3][66];
    if (t < 3 * NB) {
        const int p = t >> 6;        // 0..2
        const int b = t & 63;        // 0..63
        const float* ep = e_in + ((size_t)b * NC + c) * NK;
        const float e0 = ep[0], e1 = ep[1], e2 = ep[2];
        v4f v;
        if      (p == 0) { v.x = e0; v.y = e1; v.z = e2; v.w = e0; }
        else if (p == 1) { v.x = e1; v.y = e2; v.z = e0; v.w = e1; }
        else             { v.x = e2; v.y = e0; v.z = e1; v.w = e2; }
        e4[p][b] = v;
    }
    __syncthreads();

    const int f0 = bx * 768 + t;     // float4 index within the (b,c) slice
    const int f1 = f0 + 256;
    const int f2 = f0 + 512;
    const bool g0 = f0 < FP4, g1 = f1 < FP4, g2 = f2 < FP4;

    const v4f* a4 = reinterpret_cast<const v4f*>(a_in) + (size_t)c * FP4;
    v4f av0 = (v4f)(0.f), av1 = (v4f)(0.f), av2 = (v4f)(0.f);
    if (g0) av0 = __builtin_nontemporal_load(&a4[f0]);
    if (g1) av1 = __builtin_nontemporal_load(&a4[f1]);
    if (g2) av2 = __builtin_nontemporal_load(&a4[f2]);

    const v4f* ep0 = &e4[f0 % 3][0];
    const v4f* ep1 = &e4[f1 % 3][0];
    const v4f* ep2 = &e4[f2 % 3][0];

    v4f* o4 = reinterpret_cast<v4f*>(out);
    size_t i0 = (size_t)c * FP4 + f0;
    size_t i1 = (size_t)c * FP4 + f1;
    size_t i2 = (size_t)c * FP4 + f2;

    #pragma unroll 4
    for (int b = 0; b < NB; ++b) {
        if (g0) {
            const v4f ev = ep0[b];
            v4f o;
            o.x = fmaxf(av0.x + ev.x, 0.f);
            o.y = fmaxf(av0.y + ev.y, 0.f);
            o.z = fmaxf(av0.z + ev.z, 0.f);
            o.w = fmaxf(av0.w + ev.w, 0.f);
            __builtin_nontemporal_store(o, &o4[i0]);
        }
        if (g1) {
            const v4f ev = ep1[b];
            v4f o;
            o.x = fmaxf(av1.x + ev.x, 0.f);
            o.y = fmaxf(av1.y + ev.y, 0.f);
            o.z = fmaxf(av1.z + ev.z, 0.f);
            o.w = fmaxf(av1.w + ev.w, 0.f);
            __builtin_nontemporal_store(o, &o4[i1]);
        }
        if (g2) {
            const v4f ev = ep2[b];
            v4f o;
            o.x = fmaxf(av2.x + ev.x, 0.f);
            o.y = fmaxf(av2.y + ev.y, 0.f);
            o.z = fmaxf(av2.z + ev.z, 0.f);
            o.w = fmaxf(av2.w + ev.w, 0.f);
            __builtin_nontemporal_store(o, &o4[i2]);
        }
        i0 += BSTRIDE4;
        i1 += BSTRIDE4;
        i2 += BSTRIDE4;
    }
}

// ---------------------------------------------------------------------------
// Fused fallback for the case ws_size is too small.
// ---------------------------------------------------------------------------
__global__ __launch_bounds__(256) void decoder_fused_kernel(
    const int*   __restrict__ bin_ids,
    const float* __restrict__ emb_table,
    const float* __restrict__ fc_W,
    const float* __restrict__ e_in,
    float* __restrict__ out)
{
    const int c   = blockIdx.y;
    const int tid = threadIdx.x;
    const int l   = blockIdx.x * 256 + tid;

    __shared__ float wb[NK][ND];
    __shared__ float es[NB * NK];

    if (tid < NK * ND)
        wb[tid / ND][tid % ND] = fc_W[(tid / ND) * (2 * ND) + (tid % ND)];
    if (tid < NB * NK) {
        int b = tid / NK, k = tid % NK;
        es[tid] = e_in[((size_t)b * NC + c) * NK + k];
    }
    __syncthreads();
    if (l >= NL) return;

    const int row = bin_ids[(size_t)c * NL + l];
    const float4* er = reinterpret_cast<const float4*>(emb_table + (size_t)row * ND);
    const float4* w0 = reinterpret_cast<const float4*>(wb[0]);
    const float4* w1 = reinterpret_cast<const float4*>(wb[1]);
    const float4* w2 = reinterpret_cast<const float4*>(wb[2]);

    float a0 = 0.f, a1 = 0.f, a2 = 0.f;
    #pragma unroll
    for (int i = 0; i < ND / 4; ++i) {
        float4 v  = er[i];
        float4 p0 = w0[i], p1 = w1[i], p2 = w2[i];
        a0 += v.x * p0.x + v.y * p0.y + v.z * p0.z + v.w * p0.w;
        a1 += v.x * p1.x + v.y * p1.y + v.z * p1.z + v.w * p1.w;
        a2 += v.x * p2.x + v.y * p2.y + v.z * p2.z + v.w * p2.w;
    }

    size_t obase = ((size_t)c * NL + l) * NK;
    const size_t bstride = (size_t)NC * NL * NK;
    #pragma unroll 4
    for (int b = 0; b < NB; ++b) {
        const float e0 = es[b * NK + 0];
        const float e1 = es[b * NK + 1];
        const float e2 = es[b * NK + 2];
        out[obase + 0] = fmaxf(a0 + e0, 0.f);
        out[obase + 1] = fmaxf(a1 + e1, 0.f);
        out[obase + 2] = fmaxf(a2 + e2, 0.f);
        obase += bstride;
    }
}

extern "C" void kernel_launch(void* const* d_in, const int* in_sizes, int n_in,
                              void* d_out, int out_size, void* d_ws, size_t ws_size,
                              hipStream_t stream) {
    const float* eos_emb   = (const float*)d_in[0];
    const int*   bin_ids   = (const int*)  d_in[1];
    const float* emb_table = (const float*)d_in[2];
    const float* eos_W     = (const float*)d_in[3];
    const float* eos_b     = (const float*)d_in[4];
    const float* fc_W      = (const float*)d_in[5];
    const float* fc_b      = (const float*)d_in[6];
    float*       out       = (float*)d_out;

    // ws layout: [0, 32 KB) -> e (B*C*K floats); [32 KB, ...) -> a (C*L*K floats)
    float*  e_ws = (float*)d_ws;
    const size_t a_off_bytes = 32768;
    float*  a_ws = (float*)((char*)d_ws + a_off_bytes);
    const size_t a_bytes = (size_t)NC * NL * NK * sizeof(float);

    eos_e_kernel<<<NB * NC, 64, 0, stream>>>(eos_emb, eos_W, eos_b, fc_W, fc_b, e_ws);

    if (ws_size >= a_off_bytes + a_bytes) {
        dim3 grid_a((NL + 255) / 256, NC);
        a_kernel<<<grid_a, 256, 0, stream>>>(bin_ids, emb_table, fc_W, a_ws);

        // 768 float4 per block-x chunk: ceil(19500 / 768) = 26 chunks
        dim3 grid_b((FP4 + 767) / 768, NC);
        bstream_kernel<<<grid_b, 256, 0, stream>>>(a_ws, e_ws, out);
    } else {
        dim3 grid((NL + 255) / 256, NC);
        decoder_fused_kernel<<<grid, 256, 0, stream>>>(bin_ids, emb_table, fc_W, e_ws, out);
    }
}

// Round 6
// 147.878 us; speedup vs baseline: 1.3220x; 1.0953x over previous
//
#include <hip/hip_runtime.h>

// Problem constants (from reference)
#define NB 64      // B
#define NC 23      // C
#define NL 26000   // L
#define ND 64      // D
#define NE 512     // E
#define NK 3       // K
#define NCL (NC * NL)                  // 598000
#define FP4 (NL * NK / 4)              // 19500 float4s per (b,c) slice
#define BSTRIDE4 ((size_t)NC * FP4)    // 448500 float4s per b step

typedef float v4f __attribute__((ext_vector_type(4)));

// ---------------------------------------------------------------------------
// Kernel 1: e[b,c,k] = fc_b[k] + sum_d We[k,d]*(eos_b[d] + eos_emb[b,c,:]·eos_W[d,:])
// Quad-cooperative: 4 lanes per d-row; each load instr touches 16 cache lines
// (not 64).  Two-stage reduction: quad shfl -> wave shfl -> LDS partials.
// ---------------------------------------------------------------------------
__global__ __launch_bounds__(256) void eos_e_kernel(
    const float* __restrict__ eos_emb,  // [B][C][E]
    const float* __restrict__ eos_W,    // [D][E]
    const float* __restrict__ eos_b,    // [D]
    const float* __restrict__ fc_W,     // [K][2D]
    const float* __restrict__ fc_b,     // [K]
    float* __restrict__ e_out)          // [B*C][K]
{
    const int bc = blockIdx.x;
    const int t  = threadIdx.x;
    const int q  = t & 3;       // quarter within the row
    const int d  = t >> 2;      // 0..63

    __shared__ v4f xs4[NE / 4];                 // 128 float4
    if (t < NE / 4)
        xs4[t] = reinterpret_cast<const v4f*>(eos_emb + (size_t)bc * NE)[t];
    __syncthreads();

    const v4f* wrow = reinterpret_cast<const v4f*>(eos_W + (size_t)d * NE);
    v4f acc = (v4f)(0.f);
    #pragma unroll 8
    for (int j = 0; j < NE / 16; ++j) {         // 32 iters
        const int idx = q + 4 * j;
        acc += wrow[idx] * xs4[idx];
    }
    float p = (acc.x + acc.y) + (acc.z + acc.w);
    p += __shfl_xor(p, 1, 64);
    p += __shfl_xor(p, 2, 64);
    const float eosd = p + eos_b[d];            // all 4 lanes of quad hold it

    __shared__ float part[4][NK];
    #pragma unroll
    for (int k = 0; k < NK; ++k) {
        float pk = eosd * fc_W[k * (2 * ND) + ND + d];   // We[k][d]
        pk += __shfl_xor(pk,  4, 64);
        pk += __shfl_xor(pk,  8, 64);
        pk += __shfl_xor(pk, 16, 64);
        pk += __shfl_xor(pk, 32, 64);           // sum over the wave's 16 d's
        if ((t & 63) == 0) part[t >> 6][k] = pk;
    }
    __syncthreads();
    if (t < NK)
        e_out[(size_t)bc * NK + t] =
            part[0][t] + part[1][t] + part[2][t] + part[3][t] + fc_b[t];
}

// ---------------------------------------------------------------------------
// Kernel A: a[c,l,k] = dot(emb_table[bin_ids[c,l]], Wb[k]) -> workspace.
// Quad-cooperative: 4 lanes per emb row; each load instr covers 16 full
// 64-B lines (4x fewer TA line-requests than one-row-per-lane).
// Block = 256 threads = 64 rows.  Grid 9361 blocks -> fully balanced.
// ---------------------------------------------------------------------------
__global__ __launch_bounds__(256) void a_kernel(
    const int*   __restrict__ bin_ids,    // [C][L]
    const float* __restrict__ emb_table,  // [V][D]
    const float* __restrict__ fc_W,       // [K][2D]
    float* __restrict__ a_out)            // [C][L][K]
{
    const int c = blockIdx.y;
    const int t = threadIdx.x;
    const int q = t & 3;        // quarter of the row
    const int r = t >> 2;       // local row 0..63
    const int l = blockIdx.x * 64 + r;

    __shared__ v4f wb4[NK][ND / 4];       // Wb as float4s
    if (t < NK * (ND / 4)) {
        const int k = t / (ND / 4), i = t % (ND / 4);
        wb4[k][i] = reinterpret_cast<const v4f*>(fc_W + (size_t)k * (2 * ND))[i];
    }
    __syncthreads();
    if (l >= NL) return;

    const int row = bin_ids[(size_t)c * NL + l];
    const v4f* er = reinterpret_cast<const v4f*>(emb_table + (size_t)row * ND);

    v4f s0 = (v4f)(0.f), s1 = (v4f)(0.f), s2 = (v4f)(0.f);
    #pragma unroll
    for (int j = 0; j < 4; ++j) {
        const int idx = q + 4 * j;        // lane's float4 within the row
        const v4f v = er[idx];
        s0 += v * wb4[0][idx];
        s1 += v * wb4[1][idx];
        s2 += v * wb4[2][idx];
    }
    float a0 = (s0.x + s0.y) + (s0.z + s0.w);
    float a1 = (s1.x + s1.y) + (s1.z + s1.w);
    float a2 = (s2.x + s2.y) + (s2.z + s2.w);
    a0 += __shfl_xor(a0, 1, 64); a0 += __shfl_xor(a0, 2, 64);
    a1 += __shfl_xor(a1, 1, 64); a1 += __shfl_xor(a1, 2, 64);
    a2 += __shfl_xor(a2, 1, 64); a2 += __shfl_xor(a2, 2, 64);

    if (q < NK) {
        const float val = (q == 0) ? a0 : (q == 1) ? a1 : a2;
        a_out[((size_t)c * NL + l) * NK + q] = val;
    }
}

// ---------------------------------------------------------------------------
// Kernel B: b-stream store.  Block = (l-chunk of 768 float4, c, b-group of 16).
// 2392 blocks (9.3/CU, <=7% imbalance).  Each thread holds 3 a-float4s in
// registers; per b: 3 LDS broadcast reads + 3 contiguous regular float4
// stores (12 KB contiguous run per block per b).
// ---------------------------------------------------------------------------
__global__ __launch_bounds__(256) void bstream_kernel(
    const float* __restrict__ a_in,   // [C][L][K] floats (= C*19500 float4)
    const float* __restrict__ e_in,   // [B*C][K]
    float* __restrict__ out)          // [B][C][L][K]
{
    const int bx = blockIdx.x;
    const int c  = blockIdx.y;
    const int b0 = blockIdx.z * 16;   // b-group start
    const int t  = threadIdx.x;

    // e4[p][bl] = phase-rotated e vector for b = b0+bl
    __shared__ v4f e4[3][17];
    if (t < 3 * 16) {
        const int p  = t >> 4;        // 0..2
        const int bl = t & 15;        // 0..15
        const float* ep = e_in + ((size_t)(b0 + bl) * NC + c) * NK;
        const float e0 = ep[0], e1 = ep[1], e2 = ep[2];
        v4f v;
        if      (p == 0) { v.x = e0; v.y = e1; v.z = e2; v.w = e0; }
        else if (p == 1) { v.x = e1; v.y = e2; v.z = e0; v.w = e1; }
        else             { v.x = e2; v.y = e0; v.z = e1; v.w = e2; }
        e4[p][bl] = v;
    }
    __syncthreads();

    const int f0 = bx * 768 + t;      // float4 index within the (b,c) slice
    const int f1 = f0 + 256;
    const int f2 = f0 + 512;
    const bool g0 = f0 < FP4, g1 = f1 < FP4, g2 = f2 < FP4;

    const v4f* a4 = reinterpret_cast<const v4f*>(a_in) + (size_t)c * FP4;
    v4f av0 = (v4f)(0.f), av1 = (v4f)(0.f), av2 = (v4f)(0.f);
    if (g0) av0 = a4[f0];
    if (g1) av1 = a4[f1];
    if (g2) av2 = a4[f2];

    const v4f* ep0 = &e4[f0 % 3][0];
    const v4f* ep1 = &e4[f1 % 3][0];
    const v4f* ep2 = &e4[f2 % 3][0];

    v4f* o4 = reinterpret_cast<v4f*>(out);
    size_t i0 = (size_t)b0 * BSTRIDE4 + (size_t)c * FP4 + f0;
    size_t i1 = i0 + 256;
    size_t i2 = i0 + 512;

    #pragma unroll 4
    for (int bl = 0; bl < 16; ++bl) {
        if (g0) {
            const v4f ev = ep0[bl];
            v4f o;
            o.x = fmaxf(av0.x + ev.x, 0.f);
            o.y = fmaxf(av0.y + ev.y, 0.f);
            o.z = fmaxf(av0.z + ev.z, 0.f);
            o.w = fmaxf(av0.w + ev.w, 0.f);
            o4[i0] = o;
        }
        if (g1) {
            const v4f ev = ep1[bl];
            v4f o;
            o.x = fmaxf(av1.x + ev.x, 0.f);
            o.y = fmaxf(av1.y + ev.y, 0.f);
            o.z = fmaxf(av1.z + ev.z, 0.f);
            o.w = fmaxf(av1.w + ev.w, 0.f);
            o4[i1] = o;
        }
        if (g2) {
            const v4f ev = ep2[bl];
            v4f o;
            o.x = fmaxf(av2.x + ev.x, 0.f);
            o.y = fmaxf(av2.y + ev.y, 0.f);
            o.z = fmaxf(av2.z + ev.z, 0.f);
            o.w = fmaxf(av2.w + ev.w, 0.f);
            o4[i2] = o;
        }
        i0 += BSTRIDE4;
        i1 += BSTRIDE4;
        i2 += BSTRIDE4;
    }
}

// ---------------------------------------------------------------------------
// Fused fallback for the case ws_size is too small.
// ---------------------------------------------------------------------------
__global__ __launch_bounds__(256) void decoder_fused_kernel(
    const int*   __restrict__ bin_ids,
    const float* __restrict__ emb_table,
    const float* __restrict__ fc_W,
    const float* __restrict__ e_in,
    float* __restrict__ out)
{
    const int c   = blockIdx.y;
    const int tid = threadIdx.x;
    const int l   = blockIdx.x * 256 + tid;

    __shared__ float wb[NK][ND];
    __shared__ float es[NB * NK];

    if (tid < NK * ND)
        wb[tid / ND][tid % ND] = fc_W[(tid / ND) * (2 * ND) + (tid % ND)];
    if (tid < NB * NK) {
        int b = tid / NK, k = tid % NK;
        es[tid] = e_in[((size_t)b * NC + c) * NK + k];
    }
    __syncthreads();
    if (l >= NL) return;

    const int row = bin_ids[(size_t)c * NL + l];
    const float4* er = reinterpret_cast<const float4*>(emb_table + (size_t)row * ND);
    const float4* w0 = reinterpret_cast<const float4*>(wb[0]);
    const float4* w1 = reinterpret_cast<const float4*>(wb[1]);
    const float4* w2 = reinterpret_cast<const float4*>(wb[2]);

    float a0 = 0.f, a1 = 0.f, a2 = 0.f;
    #pragma unroll
    for (int i = 0; i < ND / 4; ++i) {
        float4 v  = er[i];
        float4 p0 = w0[i], p1 = w1[i], p2 = w2[i];
        a0 += v.x * p0.x + v.y * p0.y + v.z * p0.z + v.w * p0.w;
        a1 += v.x * p1.x + v.y * p1.y + v.z * p1.z + v.w * p1.w;
        a2 += v.x * p2.x + v.y * p2.y + v.z * p2.z + v.w * p2.w;
    }

    size_t obase = ((size_t)c * NL + l) * NK;
    const size_t bstride = (size_t)NC * NL * NK;
    #pragma unroll 4
    for (int b = 0; b < NB; ++b) {
        const float e0 = es[b * NK + 0];
        const float e1 = es[b * NK + 1];
        const float e2 = es[b * NK + 2];
        out[obase + 0] = fmaxf(a0 + e0, 0.f);
        out[obase + 1] = fmaxf(a1 + e1, 0.f);
        out[obase + 2] = fmaxf(a2 + e2, 0.f);
        obase += bstride;
    }
}

extern "C" void kernel_launch(void* const* d_in, const int* in_sizes, int n_in,
                              void* d_out, int out_size, void* d_ws, size_t ws_size,
                              hipStream_t stream) {
    const float* eos_emb   = (const float*)d_in[0];
    const int*   bin_ids   = (const int*)  d_in[1];
    const float* emb_table = (const float*)d_in[2];
    const float* eos_W     = (const float*)d_in[3];
    const float* eos_b     = (const float*)d_in[4];
    const float* fc_W      = (const float*)d_in[5];
    const float* fc_b      = (const float*)d_in[6];
    float*       out       = (float*)d_out;

    // ws layout: [0, 32 KB) -> e (B*C*K floats); [32 KB, ...) -> a (C*L*K floats)
    float*  e_ws = (float*)d_ws;
    const size_t a_off_bytes = 32768;
    float*  a_ws = (float*)((char*)d_ws + a_off_bytes);
    const size_t a_bytes = (size_t)NC * NL * NK * sizeof(float);

    eos_e_kernel<<<NB * NC, 256, 0, stream>>>(eos_emb, eos_W, eos_b, fc_W, fc_b, e_ws);

    if (ws_size >= a_off_bytes + a_bytes) {
        dim3 grid_a((NL + 63) / 64, NC);            // 407 x 23 = 9361 blocks
        a_kernel<<<grid_a, 256, 0, stream>>>(bin_ids, emb_table, fc_W, a_ws);

        dim3 grid_b((FP4 + 767) / 768, NC, 4);      // 26 x 23 x 4 = 2392 blocks
        bstream_kernel<<<grid_b, 256, 0, stream>>>(a_ws, e_ws, out);
    } else {
        dim3 grid((NL + 255) / 256, NC);
        decoder_fused_kernel<<<grid, 256, 0, stream>>>(bin_ids, emb_table, fc_W, e_ws, out);
    }
}

// Round 7
// 146.593 us; speedup vs baseline: 1.3336x; 1.0088x over previous
//
#include <hip/hip_runtime.h>

// Problem constants (from reference)
#define NB 64      // B
#define NC 23      // C
#define NL 26000   // L
#define ND 64      // D
#define NE 512     // E
#define NK 3       // K
#define FP4  (NL * NK / 4)          // 19500 float4 per (b,c) slice
#define CFP4 (NC * FP4)             // 448500 float4 per b slice (contiguous!)
#define CHUNK 3504                  // float4 per block chunk (56 KB)
#define NCHUNK 128                  // 128 * 3504 = 448512 >= 448500
#define NJ 14                       // ceil(CHUNK / 256)
#define GB 8                        // b's per block (grid.y = 8)

typedef float v4f __attribute__((ext_vector_type(4)));

// ---------------------------------------------------------------------------
// Kernel 1: e[b,c,k] = fc_b[k] + sum_d We[k,d]*(eos_b[d] + eos_emb[b,c,:]·eos_W[d,:])
// Quad-cooperative loads (full 64-B lines per quad). Two-stage reduction.
// ---------------------------------------------------------------------------
__global__ __launch_bounds__(256) void eos_e_kernel(
    const float* __restrict__ eos_emb,  // [B][C][E]
    const float* __restrict__ eos_W,    // [D][E]
    const float* __restrict__ eos_b,    // [D]
    const float* __restrict__ fc_W,     // [K][2D]
    const float* __restrict__ fc_b,     // [K]
    float* __restrict__ e_out)          // [B*C][K]
{
    const int bc = blockIdx.x;
    const int t  = threadIdx.x;
    const int q  = t & 3;       // quarter within the row
    const int d  = t >> 2;      // 0..63

    __shared__ v4f xs4[NE / 4];                 // 128 float4
    if (t < NE / 4)
        xs4[t] = reinterpret_cast<const v4f*>(eos_emb + (size_t)bc * NE)[t];
    __syncthreads();

    const v4f* wrow = reinterpret_cast<const v4f*>(eos_W + (size_t)d * NE);
    v4f acc = (v4f)(0.f);
    #pragma unroll 8
    for (int j = 0; j < NE / 16; ++j) {         // 32 iters
        const int idx = q + 4 * j;
        acc += wrow[idx] * xs4[idx];
    }
    float p = (acc.x + acc.y) + (acc.z + acc.w);
    p += __shfl_xor(p, 1, 64);
    p += __shfl_xor(p, 2, 64);
    const float eosd = p + eos_b[d];            // all 4 lanes of quad hold it

    __shared__ float part[4][NK];
    #pragma unroll
    for (int k = 0; k < NK; ++k) {
        float pk = eosd * fc_W[k * (2 * ND) + ND + d];   // We[k][d]
        pk += __shfl_xor(pk,  4, 64);
        pk += __shfl_xor(pk,  8, 64);
        pk += __shfl_xor(pk, 16, 64);
        pk += __shfl_xor(pk, 32, 64);
        if ((t & 63) == 0) part[t >> 6][k] = pk;
    }
    __syncthreads();
    if (t < NK)
        e_out[(size_t)bc * NK + t] =
            part[0][t] + part[1][t] + part[2][t] + part[3][t] + fc_b[t];
}

// ---------------------------------------------------------------------------
// Kernel A: a[c,l,k] = dot(emb_table[bin_ids[c,l]], Wb[k]) -> workspace.
// Quad-cooperative: each load instr covers 16 full 64-B lines.
// ---------------------------------------------------------------------------
__global__ __launch_bounds__(256) void a_kernel(
    const int*   __restrict__ bin_ids,    // [C][L]
    const float* __restrict__ emb_table,  // [V][D]
    const float* __restrict__ fc_W,       // [K][2D]
    float* __restrict__ a_out)            // [C][L][K]
{
    const int c = blockIdx.y;
    const int t = threadIdx.x;
    const int q = t & 3;        // quarter of the row
    const int r = t >> 2;       // local row 0..63
    const int l = blockIdx.x * 64 + r;

    __shared__ v4f wb4[NK][ND / 4];
    if (t < NK * (ND / 4)) {
        const int k = t / (ND / 4), i = t % (ND / 4);
        wb4[k][i] = reinterpret_cast<const v4f*>(fc_W + (size_t)k * (2 * ND))[i];
    }
    __syncthreads();
    if (l >= NL) return;

    const int row = bin_ids[(size_t)c * NL + l];
    const v4f* er = reinterpret_cast<const v4f*>(emb_table + (size_t)row * ND);

    v4f s0 = (v4f)(0.f), s1 = (v4f)(0.f), s2 = (v4f)(0.f);
    #pragma unroll
    for (int j = 0; j < 4; ++j) {
        const int idx = q + 4 * j;
        const v4f v = er[idx];
        s0 += v * wb4[0][idx];
        s1 += v * wb4[1][idx];
        s2 += v * wb4[2][idx];
    }
    float a0 = (s0.x + s0.y) + (s0.z + s0.w);
    float a1 = (s1.x + s1.y) + (s1.z + s1.w);
    float a2 = (s2.x + s2.y) + (s2.z + s2.w);
    a0 += __shfl_xor(a0, 1, 64); a0 += __shfl_xor(a0, 2, 64);
    a1 += __shfl_xor(a1, 1, 64); a1 += __shfl_xor(a1, 2, 64);
    a2 += __shfl_xor(a2, 1, 64); a2 += __shfl_xor(a2, 2, 64);

    if (q < NK) {
        const float val = (q == 0) ? a0 : (q == 1) ? a1 : a2;
        a_out[((size_t)c * NL + l) * NK + q] = val;
    }
}

// ---------------------------------------------------------------------------
// Kernel B: flattened b-stream store.  a and each b-slice of out are the SAME
// contiguous 448500-float4 layout, so blocks span c-boundaries freely.
// Grid = 128 chunks x 8 b-groups = 1024 blocks = exactly 4/CU (zero tail).
// Each thread holds 14 a-float4s in registers; per b: 14 LDS broadcast reads
// + 14 stores forming one contiguous 56 KB run per block.
// ---------------------------------------------------------------------------
__global__ __launch_bounds__(256) void bstream_kernel(
    const float* __restrict__ a_in,   // [CFP4] float4 (= [C][L][K] floats)
    const float* __restrict__ e_in,   // [B*C][K]
    float* __restrict__ out)          // [B][CFP4] float4
{
    const int bx = blockIdx.x;        // chunk 0..127
    const int b0 = blockIdx.y * GB;   // b-group start
    const int t  = threadIdx.x;

    // e4[p][c][bl]: phase-p rotation of e[b0+bl, c, 0..2]
    __shared__ v4f e4[3][NC][GB];
    for (int i = t; i < 3 * NC * GB; i += 256) {
        const int p   = i / (NC * GB);
        const int rem = i - p * (NC * GB);
        const int c   = rem / GB;
        const int bl  = rem - c * GB;
        const float* ep = e_in + ((size_t)(b0 + bl) * NC + c) * NK;
        const float e0 = ep[0], e1 = ep[1], e2 = ep[2];
        v4f v;
        if      (p == 0) { v.x = e0; v.y = e1; v.z = e2; v.w = e0; }
        else if (p == 1) { v.x = e1; v.y = e2; v.z = e0; v.w = e1; }
        else             { v.x = e2; v.y = e0; v.z = e1; v.w = e2; }
        e4[p][c][bl] = v;
    }
    __syncthreads();

    const int base = bx * CHUNK;
    const v4f* a4 = reinterpret_cast<const v4f*>(a_in);

    v4f        av[NJ];
    const v4f* eptr[NJ];
    bool       gj[NJ];
    #pragma unroll
    for (int j = 0; j < NJ; ++j) {
        const int fo = j * 256 + t;
        const int f  = base + fo;
        gj[j] = (fo < CHUNK) && (f < CFP4);
        const int fc = gj[j] ? f : 0;
        const int p  = fc % 3;            // k-phase of this float4
        const int c  = fc / FP4;          // which c it belongs to
        eptr[j] = &e4[p][c][0];
        av[j]   = gj[j] ? a4[fc] : (v4f)(0.f);
    }

    v4f* o4 = reinterpret_cast<v4f*>(out);
    size_t obase = (size_t)b0 * CFP4 + base;
    #pragma unroll 2
    for (int bl = 0; bl < GB; ++bl) {
        #pragma unroll
        for (int j = 0; j < NJ; ++j) {
            if (gj[j]) {
                const v4f ev = eptr[j][bl];
                v4f o;
                o.x = fmaxf(av[j].x + ev.x, 0.f);
                o.y = fmaxf(av[j].y + ev.y, 0.f);
                o.z = fmaxf(av[j].z + ev.z, 0.f);
                o.w = fmaxf(av[j].w + ev.w, 0.f);
                o4[obase + j * 256 + t] = o;
            }
        }
        obase += CFP4;
    }
}

// ---------------------------------------------------------------------------
// Fused fallback for the case ws_size is too small.
// ---------------------------------------------------------------------------
__global__ __launch_bounds__(256) void decoder_fused_kernel(
    const int*   __restrict__ bin_ids,
    const float* __restrict__ emb_table,
    const float* __restrict__ fc_W,
    const float* __restrict__ e_in,
    float* __restrict__ out)
{
    const int c   = blockIdx.y;
    const int tid = threadIdx.x;
    const int l   = blockIdx.x * 256 + tid;

    __shared__ float wb[NK][ND];
    __shared__ float es[NB * NK];

    if (tid < NK * ND)
        wb[tid / ND][tid % ND] = fc_W[(tid / ND) * (2 * ND) + (tid % ND)];
    if (tid < NB * NK) {
        int b = tid / NK, k = tid % NK;
        es[tid] = e_in[((size_t)b * NC + c) * NK + k];
    }
    __syncthreads();
    if (l >= NL) return;

    const int row = bin_ids[(size_t)c * NL + l];
    const float4* er = reinterpret_cast<const float4*>(emb_table + (size_t)row * ND);
    const float4* w0 = reinterpret_cast<const float4*>(wb[0]);
    const float4* w1 = reinterpret_cast<const float4*>(wb[1]);
    const float4* w2 = reinterpret_cast<const float4*>(wb[2]);

    float a0 = 0.f, a1 = 0.f, a2 = 0.f;
    #pragma unroll
    for (int i = 0; i < ND / 4; ++i) {
        float4 v  = er[i];
        float4 p0 = w0[i], p1 = w1[i], p2 = w2[i];
        a0 += v.x * p0.x + v.y * p0.y + v.z * p0.z + v.w * p0.w;
        a1 += v.x * p1.x + v.y * p1.y + v.z * p1.z + v.w * p1.w;
        a2 += v.x * p2.x + v.y * p2.y + v.z * p2.z + v.w * p2.w;
    }

    size_t obase = ((size_t)c * NL + l) * NK;
    const size_t bstride = (size_t)NC * NL * NK;
    #pragma unroll 4
    for (int b = 0; b < NB; ++b) {
        const float e0 = es[b * NK + 0];
        const float e1 = es[b * NK + 1];
        const float e2 = es[b * NK + 2];
        out[obase + 0] = fmaxf(a0 + e0, 0.f);
        out[obase + 1] = fmaxf(a1 + e1, 0.f);
        out[obase + 2] = fmaxf(a2 + e2, 0.f);
        obase += bstride;
    }
}

extern "C" void kernel_launch(void* const* d_in, const int* in_sizes, int n_in,
                              void* d_out, int out_size, void* d_ws, size_t ws_size,
                              hipStream_t stream) {
    const float* eos_emb   = (const float*)d_in[0];
    const int*   bin_ids   = (const int*)  d_in[1];
    const float* emb_table = (const float*)d_in[2];
    const float* eos_W     = (const float*)d_in[3];
    const float* eos_b     = (const float*)d_in[4];
    const float* fc_W      = (const float*)d_in[5];
    const float* fc_b      = (const float*)d_in[6];
    float*       out       = (float*)d_out;

    // ws layout: [0, 32 KB) -> e (B*C*K floats); [32 KB, ...) -> a (C*L*K floats)
    float*  e_ws = (float*)d_ws;
    const size_t a_off_bytes = 32768;
    float*  a_ws = (float*)((char*)d_ws + a_off_bytes);
    const size_t a_bytes = (size_t)NC * NL * NK * sizeof(float);

    eos_e_kernel<<<NB * NC, 256, 0, stream>>>(eos_emb, eos_W, eos_b, fc_W, fc_b, e_ws);

    if (ws_size >= a_off_bytes + a_bytes) {
        dim3 grid_a((NL + 63) / 64, NC);            // 407 x 23 = 9361 blocks
        a_kernel<<<grid_a, 256, 0, stream>>>(bin_ids, emb_table, fc_W, a_ws);

        dim3 grid_b(NCHUNK, NB / GB);               // 128 x 8 = 1024 blocks (4/CU)
        bstream_kernel<<<grid_b, 256, 0, stream>>>(a_ws, e_ws, out);
    } else {
        dim3 grid((NL + 255) / 256, NC);
        decoder_fused_kernel<<<grid, 256, 0, stream>>>(bin_ids, emb_table, fc_W, e_ws, out);
    }
}